// Round 12
// baseline (871.937 us; speedup 1.0000x reference)
//
#include <hip/hip_runtime.h>
#include <hip/hip_fp16.h>
#include <cstdint>

#define HIDDEN 128
#define MTOT 16
#define MAXT 10    // edges per 32-lane group (E=1.6M, ngroups=160000)
#define NPHASE 4   // dst-window phases; q-slice per phase = 3.2MB (fits 4MB L2)

typedef float vfloat4 __attribute__((ext_vector_type(4)));

// ---------------------------------------------------------------------------
// Zero-fill d_out (harness poisons d_out with 0xAA; graph must re-zero).
// ---------------------------------------------------------------------------
__global__ __launch_bounds__(256) void zero_kernel(float4* __restrict__ out,
                                                   int n4) {
  int i = blockIdx.x * 256 + threadIdx.x;
  int stride = gridDim.x * 256;
  float4 z = {0.f, 0.f, 0.f, 0.f};
  for (; i < n4; i += stride) out[i] = z;
}

// ---------------------------------------------------------------------------
// q/k projection, fp16 output. W in LDS, float4-preserving XOR swizzle.
// 8-row unroll: one ds_read_b128 feeds 32 FMAs.
// ---------------------------------------------------------------------------
__global__ __launch_bounds__(256) void proj_kernel(
    const float* __restrict__ x, const float* __restrict__ W,
    __half* __restrict__ out, int n_rows, float scale) {
  __shared__ float sW[128 * 128];  // 64 KB, swizzled
  for (int i = threadIdx.x; i < 128 * 128; i += 256) {
    int j = i >> 7, d = i & 127;
    sW[j * 128 + (d ^ ((j & 7) << 2))] = W[i] * scale;
  }
  __syncthreads();

  const int col = threadIdx.x & 127;
  const int g   = threadIdx.x >> 7;
  const int sx  = (col & 7) << 2;
  const float* sWc = sW + col * 128;

  const int row0 = blockIdx.x * 64;
#pragma unroll 1
  for (int m = 0; m < 4; ++m) {
    int r0 = row0 + g * 8 + m * 16;
    if (r0 >= n_rows) break;
    const float4* x4 = (const float4*)(x + (size_t)r0 * HIDDEN);
    if (r0 + 7 < n_rows) {
      float a0 = 0.f, a1 = 0.f, a2 = 0.f, a3 = 0.f;
      float a4 = 0.f, a5 = 0.f, a6 = 0.f, a7 = 0.f;
#pragma unroll
      for (int d4 = 0; d4 < 32; ++d4) {
        float4 w4 = *(const float4*)(sWc + ((d4 << 2) ^ sx));
        float4 xv0 = x4[d4];
        float4 xv1 = x4[32 + d4];
        float4 xv2 = x4[64 + d4];
        float4 xv3 = x4[96 + d4];
        float4 xv4 = x4[128 + d4];
        float4 xv5 = x4[160 + d4];
        float4 xv6 = x4[192 + d4];
        float4 xv7 = x4[224 + d4];
        a0 += xv0.x * w4.x + xv0.y * w4.y + xv0.z * w4.z + xv0.w * w4.w;
        a1 += xv1.x * w4.x + xv1.y * w4.y + xv1.z * w4.z + xv1.w * w4.w;
        a2 += xv2.x * w4.x + xv2.y * w4.y + xv2.z * w4.z + xv2.w * w4.w;
        a3 += xv3.x * w4.x + xv3.y * w4.y + xv3.z * w4.z + xv3.w * w4.w;
        a4 += xv4.x * w4.x + xv4.y * w4.y + xv4.z * w4.z + xv4.w * w4.w;
        a5 += xv5.x * w4.x + xv5.y * w4.y + xv5.z * w4.z + xv5.w * w4.w;
        a6 += xv6.x * w4.x + xv6.y * w4.y + xv6.z * w4.z + xv6.w * w4.w;
        a7 += xv7.x * w4.x + xv7.y * w4.y + xv7.z * w4.z + xv7.w * w4.w;
      }
      out[(size_t)(r0 + 0) * HIDDEN + col] = __float2half(a0);
      out[(size_t)(r0 + 1) * HIDDEN + col] = __float2half(a1);
      out[(size_t)(r0 + 2) * HIDDEN + col] = __float2half(a2);
      out[(size_t)(r0 + 3) * HIDDEN + col] = __float2half(a3);
      out[(size_t)(r0 + 4) * HIDDEN + col] = __float2half(a4);
      out[(size_t)(r0 + 5) * HIDDEN + col] = __float2half(a5);
      out[(size_t)(r0 + 6) * HIDDEN + col] = __float2half(a6);
      out[(size_t)(r0 + 7) * HIDDEN + col] = __float2half(a7);
    } else {
      for (int r = r0; r < n_rows; ++r) {
        const float4* xr = (const float4*)(x + (size_t)r * HIDDEN);
        float a = 0.f;
        for (int d4 = 0; d4 < 32; ++d4) {
          float4 w4 = *(const float4*)(sWc + ((d4 << 2) ^ sx));
          float4 xv = xr[d4];
          a += xv.x * w4.x + xv.y * w4.y + xv.z * w4.z + xv.w * w4.w;
        }
        out[(size_t)r * HIDDEN + col] = __float2half(a);
      }
    }
  }
}

// ---------------------------------------------------------------------------
// Edge kernel, dst-PHASED (gather-L3-bandwidth attack).
// Preload all 10 (src,dst,cutoff) triples into registers, then make NPHASE
// register-resident passes: pass p processes only edges whose dst falls in
// [p*wsize, (p+1)*wsize). At any time each XCD's q-gathers hit a 3.2MB
// L2-resident slice (streams are nt so they don't evict it) and atomics land
// in an 800KB window. w/sph/ei order stays perfectly sequential (R7 lesson).
// Guards are group-uniform (dst shared by all 32 lanes of a group).
// ---------------------------------------------------------------------------
__global__ __launch_bounds__(256) void edge_kernel(
    const __half* __restrict__ q, const __half* __restrict__ k,
    const float* __restrict__ w_ij, const float* __restrict__ sph,
    const int* __restrict__ ei, const float* __restrict__ cutoff,
    float* __restrict__ out, int E, int ngroups, int nb8, int wsize) {
  const int rank     = (blockIdx.x & 7) * nb8 + (blockIdx.x >> 3);
  const int gid      = rank * 8 + (threadIdx.x >> 5);
  const int lane     = threadIdx.x & 31;
  const int halfbase = threadIdx.x & 32;
  // m -> head: m0->h0, m1..3->h1, m4..8->h2, m9..15->h3
  const int h_for_m  = (lane >= 1) + (lane >= 4) + (lane >= 9);
  const int srcLane  = halfbase + (h_for_m << 3);

  if (gid >= E) return;
  const int cnt = (E - 1 - gid) / ngroups + 1;  // == 10 at harness sizes

  // --- preload all edge triples into registers (static indexing) ---
  int srcs[MAXT], dsts[MAXT];
  float cuts[MAXT];
#pragma unroll
  for (int t = 0; t < MAXT; ++t) {
    if (t < cnt) {
      const int e = gid + t * ngroups;
      srcs[t] = __builtin_nontemporal_load(ei + e);
      dsts[t] = __builtin_nontemporal_load(ei + E + e);
      cuts[t] = __builtin_nontemporal_load(cutoff + e);
    }
  }

#pragma unroll 1
  for (int p = 0; p < NPHASE; ++p) {
    const int lo = p * wsize;
#pragma unroll
    for (int t = 0; t < MAXT; ++t) {
      if (t < cnt && (unsigned)(dsts[t] - lo) < (unsigned)wsize) {
        const int e = gid + t * ngroups;
        const int src = srcs[t];
        const int dst = dsts[t];
        vfloat4 w4 = __builtin_nontemporal_load(
            (const vfloat4*)(w_ij + (size_t)e * HIDDEN) + lane);
        union { uint2 u; __half2 h2[2]; } qa, ka;
        qa.u = *((const uint2*)(q + (size_t)dst * HIDDEN) + lane);
        ka.u = *((const uint2*)(k + (size_t)src * HIDDEN) + lane);
        float2 q01 = __half22float2(qa.h2[0]);
        float2 q23 = __half22float2(qa.h2[1]);
        float2 k01 = __half22float2(ka.h2[0]);
        float2 k23 = __half22float2(ka.h2[1]);
        float pr = q01.x * w4.x * k01.x + q01.y * w4.y * k01.y +
                   q23.x * w4.z * k23.x + q23.y * w4.w * k23.y;
        pr += __shfl_xor(pr, 1);
        pr += __shfl_xor(pr, 2);
        pr += __shfl_xor(pr, 4);
        float alpha = pr * cuts[t];
        float am = __shfl(alpha, srcLane);
        if (lane < 16) {
          float s = __builtin_nontemporal_load(sph + (size_t)e * MTOT + lane);
          atomicAdd(out + (size_t)dst * MTOT + lane, am * s);
        }
      }
    }
  }
}

extern "C" void kernel_launch(void* const* d_in, const int* in_sizes, int n_in,
                              void* d_out, int out_size, void* d_ws, size_t ws_size,
                              hipStream_t stream) {
  // inputs: chi, sph_ij, x, w_ij, edge_index, cutoff, Wq, Wk
  const float* sph    = (const float*)d_in[1];
  const float* x      = (const float*)d_in[2];
  const float* w_ij   = (const float*)d_in[3];
  const int*   ei     = (const int*)d_in[4];
  const float* cutoff = (const float*)d_in[5];
  const float* Wq     = (const float*)d_in[6];
  const float* Wk     = (const float*)d_in[7];
  float* out = (float*)d_out;

  const int n_nodes = in_sizes[0] / MTOT;  // chi is [N, 16]
  const int E       = in_sizes[5];         // cutoff is [E, 1]

  __half* q = (__half*)d_ws;
  __half* k = q + (size_t)n_nodes * HIDDEN;

  const int n4 = out_size / 4;
  zero_kernel<<<256, 256, 0, stream>>>((float4*)out, n4);

  const int pgrid = (n_nodes + 63) / 64;
  const float inv_sqrt_hd = 0.17677669529663687f;  // 1/sqrt(32)
  proj_kernel<<<pgrid, 256, 0, stream>>>(x, Wq, q, n_nodes, inv_sqrt_hd);
  proj_kernel<<<pgrid, 256, 0, stream>>>(x, Wk, k, n_nodes, 1.0f);

  const int NB = 20000;  // multiple of 8; 160000 groups, 10 edges each
  const int ngroups = NB * 8;
  const int wsize = (n_nodes + NPHASE - 1) / NPHASE;  // 12500
  edge_kernel<<<NB, 256, 0, stream>>>(q, k, w_ij, sph, ei, cutoff, out, E,
                                      ngroups, NB / 8, wsize);
}

// Round 13
// 481.424 us; speedup vs baseline: 1.8112x; 1.8112x over previous
//
#include <hip/hip_runtime.h>
#include <hip/hip_fp16.h>
#include <cstdint>

#define HIDDEN 128
#define MTOT 16

typedef float vfloat4 __attribute__((ext_vector_type(4)));

// ---------------------------------------------------------------------------
// Zero-fill d_out (harness poisons d_out with 0xAA; graph must re-zero).
// ---------------------------------------------------------------------------
__global__ __launch_bounds__(256) void zero_kernel(float4* __restrict__ out,
                                                   int n4) {
  int i = blockIdx.x * 256 + threadIdx.x;
  int stride = gridDim.x * 256;
  float4 z = {0.f, 0.f, 0.f, 0.f};
  for (; i < n4; i += stride) out[i] = z;
}

// ---------------------------------------------------------------------------
// q/k projection, fp16 output. W in LDS, float4-preserving XOR swizzle.
// 8-row unroll: one ds_read_b128 feeds 32 FMAs.
// ---------------------------------------------------------------------------
__global__ __launch_bounds__(256) void proj_kernel(
    const float* __restrict__ x, const float* __restrict__ W,
    __half* __restrict__ out, int n_rows, float scale) {
  __shared__ float sW[128 * 128];  // 64 KB, swizzled
  for (int i = threadIdx.x; i < 128 * 128; i += 256) {
    int j = i >> 7, d = i & 127;
    sW[j * 128 + (d ^ ((j & 7) << 2))] = W[i] * scale;
  }
  __syncthreads();

  const int col = threadIdx.x & 127;
  const int g   = threadIdx.x >> 7;
  const int sx  = (col & 7) << 2;
  const float* sWc = sW + col * 128;

  const int row0 = blockIdx.x * 64;
#pragma unroll 1
  for (int m = 0; m < 4; ++m) {
    int r0 = row0 + g * 8 + m * 16;
    if (r0 >= n_rows) break;
    const float4* x4 = (const float4*)(x + (size_t)r0 * HIDDEN);
    if (r0 + 7 < n_rows) {
      float a0 = 0.f, a1 = 0.f, a2 = 0.f, a3 = 0.f;
      float a4 = 0.f, a5 = 0.f, a6 = 0.f, a7 = 0.f;
#pragma unroll
      for (int d4 = 0; d4 < 32; ++d4) {
        float4 w4 = *(const float4*)(sWc + ((d4 << 2) ^ sx));
        float4 xv0 = x4[d4];
        float4 xv1 = x4[32 + d4];
        float4 xv2 = x4[64 + d4];
        float4 xv3 = x4[96 + d4];
        float4 xv4 = x4[128 + d4];
        float4 xv5 = x4[160 + d4];
        float4 xv6 = x4[192 + d4];
        float4 xv7 = x4[224 + d4];
        a0 += xv0.x * w4.x + xv0.y * w4.y + xv0.z * w4.z + xv0.w * w4.w;
        a1 += xv1.x * w4.x + xv1.y * w4.y + xv1.z * w4.z + xv1.w * w4.w;
        a2 += xv2.x * w4.x + xv2.y * w4.y + xv2.z * w4.z + xv2.w * w4.w;
        a3 += xv3.x * w4.x + xv3.y * w4.y + xv3.z * w4.z + xv3.w * w4.w;
        a4 += xv4.x * w4.x + xv4.y * w4.y + xv4.z * w4.z + xv4.w * w4.w;
        a5 += xv5.x * w4.x + xv5.y * w4.y + xv5.z * w4.z + xv5.w * w4.w;
        a6 += xv6.x * w4.x + xv6.y * w4.y + xv6.z * w4.z + xv6.w * w4.w;
        a7 += xv7.x * w4.x + xv7.y * w4.y + xv7.z * w4.z + xv7.w * w4.w;
      }
      out[(size_t)(r0 + 0) * HIDDEN + col] = __float2half(a0);
      out[(size_t)(r0 + 1) * HIDDEN + col] = __float2half(a1);
      out[(size_t)(r0 + 2) * HIDDEN + col] = __float2half(a2);
      out[(size_t)(r0 + 3) * HIDDEN + col] = __float2half(a3);
      out[(size_t)(r0 + 4) * HIDDEN + col] = __float2half(a4);
      out[(size_t)(r0 + 5) * HIDDEN + col] = __float2half(a5);
      out[(size_t)(r0 + 6) * HIDDEN + col] = __float2half(a6);
      out[(size_t)(r0 + 7) * HIDDEN + col] = __float2half(a7);
    } else {
      for (int r = r0; r < n_rows; ++r) {
        const float4* xr = (const float4*)(x + (size_t)r * HIDDEN);
        float a = 0.f;
        for (int d4 = 0; d4 < 32; ++d4) {
          float4 w4 = *(const float4*)(sWc + ((d4 << 2) ^ sx));
          float4 xv = xr[d4];
          a += xv.x * w4.x + xv.y * w4.y + xv.z * w4.z + xv.w * w4.w;
        }
        out[(size_t)r * HIDDEN + col] = __float2half(a);
      }
    }
  }
}

// ---------------------------------------------------------------------------
// Edge kernel (R8 structure + 4-edge unroll -> ~26 independent loads in
// flight per wave iteration; counters showed 1.5-2.1 TB/s with nothing
// saturated = concurrency-limited).
// nt only on true streams (w_ij, sph); ei/cutoff lines are reused by all 4
// waves of a block -> cacheable. sph loaded by all 32 lanes (lane&15; one
// line either way) so it joins the load burst.
// ---------------------------------------------------------------------------
__global__ __launch_bounds__(256) void edge_kernel(
    const __half* __restrict__ q, const __half* __restrict__ k,
    const float* __restrict__ w_ij, const float* __restrict__ sph,
    const int* __restrict__ ei, const float* __restrict__ cutoff,
    float* __restrict__ out, int E, int ngroups, int nb8) {
  const int rank     = (blockIdx.x & 7) * nb8 + (blockIdx.x >> 3);
  const int gid      = rank * 8 + (threadIdx.x >> 5);
  const int lane     = threadIdx.x & 31;
  const int halfbase = threadIdx.x & 32;
  const int midx     = lane & 15;
  // m -> head: m0->h0, m1..3->h1, m4..8->h2, m9..15->h3
  const int h_for_m  = (midx >= 1) + (midx >= 4) + (midx >= 9);
  const int srcLane  = halfbase + (h_for_m << 3);

  int e = gid;
  // ---- 4-edge unrolled main loop ----
  for (; e + 3 * ngroups < E; e += 4 * ngroups) {
    const int e0 = e, e1 = e + ngroups, e2 = e + 2 * ngroups,
              e3 = e + 3 * ngroups;
    // load burst: indices
    int s0 = ei[e0], s1 = ei[e1], s2 = ei[e2], s3 = ei[e3];
    int d0 = ei[E + e0], d1 = ei[E + e1], d2 = ei[E + e2], d3 = ei[E + e3];
    float c0 = cutoff[e0], c1 = cutoff[e1], c2 = cutoff[e2], c3 = cutoff[e3];
    // load burst: streams + gathers + sph
    vfloat4 w0 = __builtin_nontemporal_load(
        (const vfloat4*)(w_ij + (size_t)e0 * HIDDEN) + lane);
    vfloat4 w1 = __builtin_nontemporal_load(
        (const vfloat4*)(w_ij + (size_t)e1 * HIDDEN) + lane);
    vfloat4 w2 = __builtin_nontemporal_load(
        (const vfloat4*)(w_ij + (size_t)e2 * HIDDEN) + lane);
    vfloat4 w3 = __builtin_nontemporal_load(
        (const vfloat4*)(w_ij + (size_t)e3 * HIDDEN) + lane);
    union { uint2 u; __half2 h2[2]; } q0, q1, q2, q3, k0, k1, k2, k3;
    q0.u = *((const uint2*)(q + (size_t)d0 * HIDDEN) + lane);
    q1.u = *((const uint2*)(q + (size_t)d1 * HIDDEN) + lane);
    q2.u = *((const uint2*)(q + (size_t)d2 * HIDDEN) + lane);
    q3.u = *((const uint2*)(q + (size_t)d3 * HIDDEN) + lane);
    k0.u = *((const uint2*)(k + (size_t)s0 * HIDDEN) + lane);
    k1.u = *((const uint2*)(k + (size_t)s1 * HIDDEN) + lane);
    k2.u = *((const uint2*)(k + (size_t)s2 * HIDDEN) + lane);
    k3.u = *((const uint2*)(k + (size_t)s3 * HIDDEN) + lane);
    float sp0 = __builtin_nontemporal_load(sph + (size_t)e0 * MTOT + midx);
    float sp1 = __builtin_nontemporal_load(sph + (size_t)e1 * MTOT + midx);
    float sp2 = __builtin_nontemporal_load(sph + (size_t)e2 * MTOT + midx);
    float sp3 = __builtin_nontemporal_load(sph + (size_t)e3 * MTOT + midx);

    // compute x4 (independent chains)
    float p0, p1, p2, p3;
    {
      float2 qa = __half22float2(q0.h2[0]), qb = __half22float2(q0.h2[1]);
      float2 ka = __half22float2(k0.h2[0]), kb = __half22float2(k0.h2[1]);
      p0 = qa.x * w0.x * ka.x + qa.y * w0.y * ka.y +
           qb.x * w0.z * kb.x + qb.y * w0.w * kb.y;
    }
    {
      float2 qa = __half22float2(q1.h2[0]), qb = __half22float2(q1.h2[1]);
      float2 ka = __half22float2(k1.h2[0]), kb = __half22float2(k1.h2[1]);
      p1 = qa.x * w1.x * ka.x + qa.y * w1.y * ka.y +
           qb.x * w1.z * kb.x + qb.y * w1.w * kb.y;
    }
    {
      float2 qa = __half22float2(q2.h2[0]), qb = __half22float2(q2.h2[1]);
      float2 ka = __half22float2(k2.h2[0]), kb = __half22float2(k2.h2[1]);
      p2 = qa.x * w2.x * ka.x + qa.y * w2.y * ka.y +
           qb.x * w2.z * kb.x + qb.y * w2.w * kb.y;
    }
    {
      float2 qa = __half22float2(q3.h2[0]), qb = __half22float2(q3.h2[1]);
      float2 ka = __half22float2(k3.h2[0]), kb = __half22float2(k3.h2[1]);
      p3 = qa.x * w3.x * ka.x + qa.y * w3.y * ka.y +
           qb.x * w3.z * kb.x + qb.y * w3.w * kb.y;
    }
    p0 += __shfl_xor(p0, 1); p1 += __shfl_xor(p1, 1);
    p2 += __shfl_xor(p2, 1); p3 += __shfl_xor(p3, 1);
    p0 += __shfl_xor(p0, 2); p1 += __shfl_xor(p1, 2);
    p2 += __shfl_xor(p2, 2); p3 += __shfl_xor(p3, 2);
    p0 += __shfl_xor(p0, 4); p1 += __shfl_xor(p1, 4);
    p2 += __shfl_xor(p2, 4); p3 += __shfl_xor(p3, 4);
    float am0 = __shfl(p0 * c0, srcLane);
    float am1 = __shfl(p1 * c1, srcLane);
    float am2 = __shfl(p2 * c2, srcLane);
    float am3 = __shfl(p3 * c3, srcLane);
    if (lane < 16) {
      atomicAdd(out + (size_t)d0 * MTOT + midx, am0 * sp0);
      atomicAdd(out + (size_t)d1 * MTOT + midx, am1 * sp1);
      atomicAdd(out + (size_t)d2 * MTOT + midx, am2 * sp2);
      atomicAdd(out + (size_t)d3 * MTOT + midx, am3 * sp3);
    }
  }
  // ---- remainder (strided singles; <=3 iterations) ----
  for (; e < E; e += ngroups) {
    int src = ei[e];
    int dst = ei[E + e];
    float cut = cutoff[e];
    vfloat4 w4 = __builtin_nontemporal_load(
        (const vfloat4*)(w_ij + (size_t)e * HIDDEN) + lane);
    union { uint2 u; __half2 h2[2]; } qa, ka;
    qa.u = *((const uint2*)(q + (size_t)dst * HIDDEN) + lane);
    ka.u = *((const uint2*)(k + (size_t)src * HIDDEN) + lane);
    float sp = __builtin_nontemporal_load(sph + (size_t)e * MTOT + midx);
    float2 q01 = __half22float2(qa.h2[0]);
    float2 q23 = __half22float2(qa.h2[1]);
    float2 k01 = __half22float2(ka.h2[0]);
    float2 k23 = __half22float2(ka.h2[1]);
    float p = q01.x * w4.x * k01.x + q01.y * w4.y * k01.y +
              q23.x * w4.z * k23.x + q23.y * w4.w * k23.y;
    p += __shfl_xor(p, 1);
    p += __shfl_xor(p, 2);
    p += __shfl_xor(p, 4);
    float am = __shfl(p * cut, srcLane);
    if (lane < 16) {
      atomicAdd(out + (size_t)dst * MTOT + midx, am * sp);
    }
  }
}

extern "C" void kernel_launch(void* const* d_in, const int* in_sizes, int n_in,
                              void* d_out, int out_size, void* d_ws, size_t ws_size,
                              hipStream_t stream) {
  // inputs: chi, sph_ij, x, w_ij, edge_index, cutoff, Wq, Wk
  const float* sph    = (const float*)d_in[1];
  const float* x      = (const float*)d_in[2];
  const float* w_ij   = (const float*)d_in[3];
  const int*   ei     = (const int*)d_in[4];
  const float* cutoff = (const float*)d_in[5];
  const float* Wq     = (const float*)d_in[6];
  const float* Wk     = (const float*)d_in[7];
  float* out = (float*)d_out;

  const int n_nodes = in_sizes[0] / MTOT;  // chi is [N, 16]
  const int E       = in_sizes[5];         // cutoff is [E, 1]

  __half* q = (__half*)d_ws;
  __half* k = q + (size_t)n_nodes * HIDDEN;

  const int n4 = out_size / 4;
  zero_kernel<<<256, 256, 0, stream>>>((float4*)out, n4);

  const int pgrid = (n_nodes + 63) / 64;
  const float inv_sqrt_hd = 0.17677669529663687f;  // 1/sqrt(32)
  proj_kernel<<<pgrid, 256, 0, stream>>>(x, Wq, q, n_nodes, inv_sqrt_hd);
  proj_kernel<<<pgrid, 256, 0, stream>>>(x, Wk, k, n_nodes, 1.0f);

  const int NB = 20000;  // multiple of 8; 160000 groups, 10 edges each
  const int ngroups = NB * 8;
  edge_kernel<<<NB, 256, 0, stream>>>(q, k, w_ij, sph, ei, cutoff, out, E,
                                      ngroups, NB / 8);
}